// Round 21
// baseline (5686.954 us; speedup 1.0000x reference)
//
#include <hip/hip_runtime.h>
#include <hip/hip_bf16.h>

#define NN 50000
#define NE 1000000
#define DD 64
#define HH 4
#define LL 4
#define D3 192
#define NT (NE + NN)   // total sorted entries (edges + self loops)

typedef float f32x4 __attribute__((ext_vector_type(4)));
typedef short bf16x8 __attribute__((ext_vector_type(8)));

__device__ __forceinline__ unsigned short f2bf(float f){
    union { __hip_bfloat16 b; unsigned short u; } cv;
    cv.b = __float2bfloat16(f);
    return cv.u;
}
__device__ __forceinline__ float bf2f(unsigned short u){
    return __uint_as_float(((unsigned)u) << 16);
}
__device__ __forceinline__ unsigned pk2(float a, float b){
    union { __hip_bfloat162 v; unsigned u; } cv;
    cv.v = __float22bfloat162_rn(float2{a, b});
    return cv.u;
}
__device__ __forceinline__ float lrelu(float x){ return x > 0.f ? x : 0.2f * x; }

// ================= CSR build (once per call; topology fixed across layers) =================
__global__ __launch_bounds__(256) void k_hist(const int* __restrict__ ei, int* __restrict__ deg){
    for (int e = blockIdx.x * 256 + threadIdx.x; e < NE; e += gridDim.x * 256)
        atomicAdd(&deg[ei[NE + e]], 1);
}

__global__ __launch_bounds__(1024) void k_scan(const int* __restrict__ deg,
                                               int* __restrict__ row,
                                               int* __restrict__ cursor){
    __shared__ int sm[1024];
    __shared__ int carry_s;
    int t = threadIdx.x;
    if (t == 0) carry_s = 0;
    __syncthreads();
    for (int base = 0; base < NN; base += 1024) {
        int i = base + t;
        int v = (i < NN) ? deg[i] + 1 : 0;
        sm[t] = v;
        __syncthreads();
        for (int off = 1; off < 1024; off <<= 1) {
            int x = (t >= off) ? sm[t - off] : 0;
            __syncthreads();
            sm[t] += x;
            __syncthreads();
        }
        int incl = sm[t];
        int carry = carry_s;
        if (i < NN) {
            int excl = carry + incl - v;
            row[i] = excl;
            cursor[i] = excl;
        }
        __syncthreads();
        if (t == 1023) carry_s = carry + incl;
        __syncthreads();
    }
    if (t == 0) row[NN] = carry_s;
}

__global__ __launch_bounds__(256) void k_scatter(const int* __restrict__ ei,
                                                 int* __restrict__ cursor,
                                                 int* __restrict__ pos,
                                                 int* __restrict__ srcs){
    for (int e = blockIdx.x * 256 + threadIdx.x; e < NE; e += gridDim.x * 256) {
        int d = ei[NE + e];
        int j = atomicAdd(&cursor[d], 1);
        pos[e] = j;
        srcs[j] = ei[e];
    }
}

// self-loop entries at the end of each node's segment
__global__ __launch_bounds__(256) void k_self(const int* __restrict__ row,
                                              int* __restrict__ srcs){
    int n = blockIdx.x * 256 + threadIdx.x;
    if (n < NN) srcs[row[n + 1] - 1] = n;
}

// ================= upfront weight prep, ALL layers (fragment-major W) =================
__global__ __launch_bounds__(256) void k_prepall(const float* __restrict__ w1,
                                                 const float* __restrict__ w2,
                                                 const float* __restrict__ we,
                                                 const float* __restrict__ atte,
                                                 unsigned short* __restrict__ w1f_all,
                                                 unsigned short* __restrict__ w2f_all,
                                                 float* __restrict__ V_all){
    int l = blockIdx.x / 194;
    int i = (blockIdx.x % 194) * 256 + threadIdx.x;
    unsigned short* w1f = w1f_all + (size_t)l * D3 * D3;
    unsigned short* w2f = w2f_all + (size_t)l * DD * D3;
    float* V = V_all + l * DD * HH;
    if (i < 36864) {
        int c = i / 3072, r = i % 3072;
        int kc = r / 512, r2 = r % 512;
        int lane = r2 >> 3, m = r2 & 7;
        int k = kc * 32 + (lane >> 4) * 8 + m;
        int n = c * 16 + (lane & 15);
        w1f[i] = f2bf(w1[(size_t)l * D3 * D3 + k * D3 + n]);
    } else if (i < 49152) {
        int j = i - 36864;
        int c = j / 3072, r = j % 3072;
        int kc = r / 512, r2 = r % 512;
        int lane = r2 >> 3, m = r2 & 7;
        int k = kc * 32 + (lane >> 4) * 8 + m;
        int n = c * 16 + (lane & 15);
        w2f[j] = f2bf(w2[(size_t)l * D3 * DD + k * DD + n]);
    } else if (i < 49152 + DD * HH) {
        int j = i - 49152;
        int k = j >> 2, h = j & 3;
        float s = 0.f;
        #pragma unroll
        for (int c = 0; c < 16; c++)
            s += we[(size_t)l * DD * DD + k * DD + h * 16 + c] * atte[l * DD + h * 16 + c];
        V[j] = s;
    }
}

// ================= per-layer a_edge = ecur @ V(l), scattered to SORTED position =================
__global__ __launch_bounds__(256) void k_aedge(const float* __restrict__ ef,
                                               const int* __restrict__ pos,
                                               const float* __restrict__ Vg,
                                               float* __restrict__ aedge_s){
    __shared__ float Vl[256];
    Vl[threadIdx.x] = Vg[threadIdx.x];
    __syncthreads();
    int gk = threadIdx.x & 7;
    int em = threadIdx.x >> 3;
    int c0 = gk * 8;
    for (int eb = blockIdx.x * 32; eb < NE; eb += gridDim.x * 32) {
        int e = eb + em;
        const float4* ep = (const float4*)(ef + (size_t)e * 64 + c0);
        float4 v0 = ep[0];
        float4 v1 = ep[1];
        float p0, p1, p2, p3;
        {
            const float* Vp = &Vl[c0 * 4];
            p0 = v0.x*Vp[0] + v0.y*Vp[4] + v0.z*Vp[8]  + v0.w*Vp[12]
               + v1.x*Vp[16] + v1.y*Vp[20] + v1.z*Vp[24] + v1.w*Vp[28];
            p1 = v0.x*Vp[1] + v0.y*Vp[5] + v0.z*Vp[9]  + v0.w*Vp[13]
               + v1.x*Vp[17] + v1.y*Vp[21] + v1.z*Vp[25] + v1.w*Vp[29];
            p2 = v0.x*Vp[2] + v0.y*Vp[6] + v0.z*Vp[10] + v0.w*Vp[14]
               + v1.x*Vp[18] + v1.y*Vp[22] + v1.z*Vp[26] + v1.w*Vp[30];
            p3 = v0.x*Vp[3] + v0.y*Vp[7] + v0.z*Vp[11] + v0.w*Vp[15]
               + v1.x*Vp[19] + v1.y*Vp[23] + v1.z*Vp[27] + v1.w*Vp[31];
        }
        #pragma unroll
        for (int m = 1; m < 8; m <<= 1) {
            p0 += __shfl_xor(p0, m);
            p1 += __shfl_xor(p1, m);
            p2 += __shfl_xor(p2, m);
            p3 += __shfl_xor(p3, m);
        }
        if (gk == 0) {
            int j = pos[e];
            float4 ae = {p0, p1, p2, p3};
            *(float4*)(aedge_s + (size_t)j * 4) = ae;
        }
    }
}

// ================= node linear + attention coefficients (xh stored bf16) =================
__global__ __launch_bounds__(256) void k_nodelin(const float* __restrict__ x,
                                                 const float* __restrict__ Wg,
                                                 const float* __restrict__ attsrc,
                                                 const float* __restrict__ attdst,
                                                 unsigned short* __restrict__ xh,
                                                 float* __restrict__ a_src,
                                                 float* __restrict__ a_dst, int l){
    __shared__ float Wl[64 * 64];
    __shared__ float xr[4 * 64];
    int t = threadIdx.x;
    const float* W = Wg + (size_t)l * 4096;
    for (int i = t; i < 4096; i += 256) Wl[i] = W[i];
    int row = blockIdx.x * 4 + (t >> 6);
    int col = t & 63;
    if (row < NN) xr[t] = x[(size_t)row * 64 + col];
    __syncthreads();
    float acc = 0.f;
    const float* xp = &xr[(t >> 6) * 64];
    #pragma unroll
    for (int k = 0; k < 64; k++) acc += xp[k] * Wl[k * 64 + col];
    float ps = acc * attsrc[l * 64 + col];
    float pd = acc * attdst[l * 64 + col];
    #pragma unroll
    for (int m = 1; m < 16; m <<= 1) { ps += __shfl_xor(ps, m); pd += __shfl_xor(pd, m); }
    if (row < NN) {
        xh[(size_t)row * 64 + col] = f2bf(acc);
        if ((col & 15) == 0) {
            a_src[row * 4 + (col >> 4)] = ps;
            a_dst[row * 4 + (col >> 4)] = pd;
        }
    }
}

// ================= fused attention (round-20 proven kernel, verbatim) =================
__global__ __launch_bounds__(256) void k_attnfused(const int* __restrict__ row,
                                                   const int* __restrict__ srcs,
                                                   float* __restrict__ aedge_s,
                                                   const float* __restrict__ a_src,
                                                   const float* __restrict__ a_dst,
                                                   const unsigned short* __restrict__ xh,
                                                   const float* __restrict__ bias,
                                                   const float* __restrict__ lnw,
                                                   const float* __restrict__ lnb,
                                                   const float* __restrict__ xcur,
                                                   float* __restrict__ xnext,
                                                   unsigned short* __restrict__ xbf,
                                                   int l, int dorelu){
    int n = blockIdx.x * 4 + (threadIdx.x >> 6);
    if (n >= NN) return;
    int lane = threadIdx.x & 63;
    int a = row[n], b = row[n + 1];
    int len = b - a;

    const float4 ad = *(const float4*)(a_dst + (size_t)n * 4);
    float4 mx = {-1e30f, -1e30f, -1e30f, -1e30f};
    float4 sum = {0.f, 0.f, 0.f, 0.f};

    if (len <= 64) {
        int j = a + lane;
        bool act = lane < len;
        float4 val = {-1e30f, -1e30f, -1e30f, -1e30f};
        if (act) {
            int s = srcs[j];
            const float4 as = *(const float4*)(a_src + (size_t)s * 4);
            const float4 ae = *(const float4*)(aedge_s + (size_t)j * 4);
            val.x = lrelu(as.x + ad.x + ae.x);
            val.y = lrelu(as.y + ad.y + ae.y);
            val.z = lrelu(as.z + ad.z + ae.z);
            val.w = lrelu(as.w + ad.w + ae.w);
        }
        mx = val;
        #pragma unroll
        for (int m = 1; m < 64; m <<= 1) {
            mx.x = fmaxf(mx.x, __shfl_xor(mx.x, m));
            mx.y = fmaxf(mx.y, __shfl_xor(mx.y, m));
            mx.z = fmaxf(mx.z, __shfl_xor(mx.z, m));
            mx.w = fmaxf(mx.w, __shfl_xor(mx.w, m));
        }
        float4 ex = {0.f, 0.f, 0.f, 0.f};
        if (act) {
            ex.x = expf(val.x - mx.x);
            ex.y = expf(val.y - mx.y);
            ex.z = expf(val.z - mx.z);
            ex.w = expf(val.w - mx.w);
            *(float4*)(aedge_s + (size_t)j * 4) = ex;
        }
        sum = ex;
        #pragma unroll
        for (int m = 1; m < 64; m <<= 1) {
            sum.x += __shfl_xor(sum.x, m);
            sum.y += __shfl_xor(sum.y, m);
            sum.z += __shfl_xor(sum.z, m);
            sum.w += __shfl_xor(sum.w, m);
        }
    } else {
        for (int j0 = a; j0 < b; j0 += 64) {
            int j = j0 + lane;
            if (j < b) {
                int s = srcs[j];
                const float4 as = *(const float4*)(a_src + (size_t)s * 4);
                const float4 ae = *(const float4*)(aedge_s + (size_t)j * 4);
                mx.x = fmaxf(mx.x, lrelu(as.x + ad.x + ae.x));
                mx.y = fmaxf(mx.y, lrelu(as.y + ad.y + ae.y));
                mx.z = fmaxf(mx.z, lrelu(as.z + ad.z + ae.z));
                mx.w = fmaxf(mx.w, lrelu(as.w + ad.w + ae.w));
            }
        }
        #pragma unroll
        for (int m = 1; m < 64; m <<= 1) {
            mx.x = fmaxf(mx.x, __shfl_xor(mx.x, m));
            mx.y = fmaxf(mx.y, __shfl_xor(mx.y, m));
            mx.z = fmaxf(mx.z, __shfl_xor(mx.z, m));
            mx.w = fmaxf(mx.w, __shfl_xor(mx.w, m));
        }
        for (int j0 = a; j0 < b; j0 += 64) {
            int j = j0 + lane;
            if (j < b) {
                int s = srcs[j];
                const float4 as = *(const float4*)(a_src + (size_t)s * 4);
                const float4 ae = *(const float4*)(aedge_s + (size_t)j * 4);
                float4 ex;
                ex.x = expf(lrelu(as.x + ad.x + ae.x) - mx.x);
                ex.y = expf(lrelu(as.y + ad.y + ae.y) - mx.y);
                ex.z = expf(lrelu(as.z + ad.z + ae.z) - mx.z);
                ex.w = expf(lrelu(as.w + ad.w + ae.w) - mx.w);
                *(float4*)(aedge_s + (size_t)j * 4) = ex;
                sum.x += ex.x; sum.y += ex.y; sum.z += ex.z; sum.w += ex.w;
            }
        }
        #pragma unroll
        for (int m = 1; m < 64; m <<= 1) {
            sum.x += __shfl_xor(sum.x, m);
            sum.y += __shfl_xor(sum.y, m);
            sum.z += __shfl_xor(sum.z, m);
            sum.w += __shfl_xor(sum.w, m);
        }
    }

    int h = lane >> 4;
    float sumh = (h == 0) ? sum.x : (h == 1) ? sum.y : (h == 2) ? sum.z : sum.w;
    float invh = 1.f / (sumh + 1e-16f);

    float accv = 0.f;
    #pragma unroll 8
    for (int j = a; j < b; ++j) {
        int s = srcs[j];
        float coef = aedge_s[(size_t)j * 4 + h] * invh;
        accv = fmaf(bf2f(xh[(size_t)s * 64 + lane]), coef, accv);
    }

    if (lane < 4) aedge_s[(size_t)(b - 1) * 4 + lane] = 0.f;

    float v = accv + bias[l * 64 + lane];
    float s = v, q = v * v;
    #pragma unroll
    for (int m = 1; m < 64; m <<= 1) { s += __shfl_xor(s, m); q += __shfl_xor(q, m); }
    float mu = s * (1.f / 64.f);
    float var = q * (1.f / 64.f) - mu * mu;
    float y = (v - mu) * rsqrtf(var + 1e-5f) * lnw[l * 64 + lane] + lnb[l * 64 + lane];
    if (dorelu) y = fmaxf(y, 0.f);
    float out = y + xcur[(size_t)n * 64 + lane];
    xnext[(size_t)n * 64 + lane] = out;
    xbf[(size_t)n * 64 + lane] = f2bf(out);
}

// ---------------- edge MLP: persistent blocks, 2-deep async-stage pipeline (T14) ----------------
#define ET 64
#define EGRID 2048
__global__ __launch_bounds__(256, 2) void k_edgemlp(const unsigned short* __restrict__ xbf,
                                                    const float* __restrict__ ein,
                                                    float* __restrict__ eout,
                                                    const int* __restrict__ ei,
                                                    const unsigned short* __restrict__ w1f,
                                                    const unsigned short* __restrict__ w2f,
                                                    const float* __restrict__ b1g,
                                                    const float* __restrict__ lnwg,
                                                    const float* __restrict__ lnbg,
                                                    const float* __restrict__ b2g, int l){
    __shared__ __align__(16) unsigned short zin[ET * 192];  // 24.6KB
    __shared__ float red[ET][2][2];                         // 1KB
    __shared__ float eres[ET][68];                          // 17.4KB residual park

    const int ntiles = NE / ET;
    int t = threadIdx.x;
    int wid = t >> 6, lane = t & 63;
    int wr = wid >> 1, wc = wid & 1;
    int l15 = lane & 15, l4 = lane >> 4;
    int eb = wr * 32;
    int swz = lane & 7;

    // loop-invariant per-column constants
    float b1v[6], lnwv[6], lnbv[6];
    #pragma unroll
    for (int nt = 0; nt < 6; nt++) {
        int col = wc * 96 + nt * 16 + l15;
        b1v[nt] = b1g[l * D3 + col];
        lnwv[nt] = lnwg[l * D3 + col];
        lnbv[nt] = lnbg[l * D3 + col];
    }
    float b2v[4];
    #pragma unroll
    for (int nt = 0; nt < 4; nt++) b2v[nt] = b2g[l * 64 + nt * 16 + l15];

    // next-tile register staging (named regs; long live range is intentional)
    uint4 rx0, rx1, rx2, rx3;
    float4 re0a, re0b, re1a, re1b;

#define LOAD_TILE(T)                                                       \
    {                                                                      \
        int ge_ = (T) * ET + lane;                                         \
        int sidx_ = ei[ge_], didx_ = ei[NE + ge_];                         \
        const unsigned short* xs_ = xbf + (size_t)sidx_ * 64;              \
        const unsigned short* xd_ = xbf + (size_t)didx_ * 64;              \
        rx0 = *(const uint4*)(xs_ + wid * 8);                              \
        rx1 = *(const uint4*)(xs_ + (wid + 4) * 8);                        \
        rx2 = *(const uint4*)(xd_ + wid * 8);                              \
        rx3 = *(const uint4*)(xd_ + (wid + 4) * 8);                        \
        const float* ep_ = ein + (size_t)ge_ * 64;                         \
        re0a = *(const float4*)(ep_ + wid * 8);                            \
        re0b = *(const float4*)(ep_ + wid * 8 + 4);                        \
        re1a = *(const float4*)(ep_ + (wid + 4) * 8);                      \
        re1b = *(const float4*)(ep_ + (wid + 4) * 8 + 4);                  \
    }

    int tile = blockIdx.x;
    if (tile >= ntiles) return;
    LOAD_TILE(tile);

    for (; tile < ntiles; tile += EGRID) {
        int base = tile * ET;
        // ---- write staged regs to LDS ----
        *(uint4*)&zin[lane * 192 + (((wid)      ^ swz) << 3)] = rx0;
        *(uint4*)&zin[lane * 192 + (((wid + 4)  ^ swz) << 3)] = rx1;
        *(uint4*)&zin[lane * 192 + (((wid + 8)  ^ swz) << 3)] = rx2;
        *(uint4*)&zin[lane * 192 + (((wid + 12) ^ swz) << 3)] = rx3;
        {
            uint4 w;
            w.x = pk2(re0a.x, re0a.y); w.y = pk2(re0a.z, re0a.w);
            w.z = pk2(re0b.x, re0b.y); w.w = pk2(re0b.z, re0b.w);
            *(uint4*)&zin[lane * 192 + (((wid + 16) ^ swz) << 3)] = w;
            int c0 = wid * 8;
            eres[lane][c0 + 0] = re0a.x; eres[lane][c0 + 1] = re0a.y;
            eres[lane][c0 + 2] = re0a.z; eres[lane][c0 + 3] = re0a.w;
            eres[lane][c0 + 4] = re0b.x; eres[lane][c0 + 5] = re0b.y;
            eres[lane][c0 + 6] = re0b.z; eres[lane][c0 + 7] = re0b.w;
            w.x = pk2(re1a.x, re1a.y); w.y = pk2(re1a.z, re1a.w);
            w.z = pk2(re1b.x, re1b.y); w.w = pk2(re1b.z, re1b.w);
            *(uint4*)&zin[lane * 192 + (((wid + 20) ^ swz) << 3)] = w;
            c0 = (wid + 4) * 8;
            eres[lane][c0 + 0] = re1a.x; eres[lane][c0 + 1] = re1a.y;
            eres[lane][c0 + 2] = re1a.z; eres[lane][c0 + 3] = re1a.w;
            eres[lane][c0 + 4] = re1b.x; eres[lane][c0 + 5] = re1b.y;
            eres[lane][c0 + 6] = re1b.z; eres[lane][c0 + 7] = re1b.w;
        }
        // ---- issue next tile's loads (in flight during compute) ----
        {
            int tn = tile + EGRID;
            if (tn < ntiles) LOAD_TILE(tn);
        }
        __syncthreads();

        // ---- GEMM1 ----
        f32x4 zz = {0.f, 0.f, 0.f, 0.f};
        f32x4 acc[2][6];
        #pragma unroll
        for (int mt = 0; mt < 2; mt++)
            #pragma unroll
            for (int nt = 0; nt < 6; nt++) acc[mt][nt] = zz;

        #pragma unroll
        for (int kc = 0; kc < 6; kc++) {
            int gg = kc * 4 + l4;
            bf16x8 af[2], bfv[6];
            #pragma unroll
            for (int mt = 0; mt < 2; mt++) {
                int row = eb + mt * 16 + l15;
                af[mt] = *(const bf16x8*)&zin[row * 192 + ((gg ^ (row & 7)) << 3)];
            }
            #pragma unroll
            for (int nt = 0; nt < 6; nt++)
                bfv[nt] = *(const bf16x8*)&w1f[(size_t)(((wc * 6 + nt) * 6 + kc) << 9) + (lane << 3)];
            #pragma unroll
            for (int mt = 0; mt < 2; mt++)
                #pragma unroll
                for (int nt = 0; nt < 6; nt++)
                    acc[mt][nt] = __builtin_amdgcn_mfma_f32_16x16x32_bf16(af[mt], bfv[nt], acc[mt][nt], 0, 0, 0);
        }

        // ---- +b1, LN partials ----
        float ps[2][4], pq[2][4];
        #pragma unroll
        for (int mt = 0; mt < 2; mt++)
            #pragma unroll
            for (int r = 0; r < 4; r++) {
                float s = 0.f, q = 0.f;
                #pragma unroll
                for (int nt = 0; nt < 6; nt++) {
                    float v = acc[mt][nt][r] + b1v[nt];
                    acc[mt][nt][r] = v;
                    s += v; q += v * v;
                }
                #pragma unroll
                for (int m = 1; m < 16; m <<= 1) { s += __shfl_xor(s, m); q += __shfl_xor(q, m); }
                ps[mt][r] = s; pq[mt][r] = q;
            }
        if (l15 == 0) {
            #pragma unroll
            for (int mt = 0; mt < 2; mt++)
                #pragma unroll
                for (int r = 0; r < 4; r++) {
                    int er = eb + mt * 16 + l4 * 4 + r;
                    red[er][wc][0] = ps[mt][r];
                    red[er][wc][1] = pq[mt][r];
                }
        }
        __syncthreads();

        // ---- normalize + relu -> h1 (reuse zin, same swizzle) ----
        #pragma unroll
        for (int mt = 0; mt < 2; mt++)
            #pragma unroll
            for (int r = 0; r < 4; r++) {
                int er = eb + mt * 16 + l4 * 4 + r;
                float s = red[er][0][0] + red[er][1][0];
                float q = red[er][0][1] + red[er][1][1];
                float mu = s * (1.f / 192.f);
                float rs = rsqrtf(q * (1.f / 192.f) - mu * mu + 1e-5f);
                #pragma unroll
                for (int nt = 0; nt < 6; nt++) {
                    float v = (acc[mt][nt][r] - mu) * rs * lnwv[nt] + lnbv[nt];
                    v = fmaxf(v, 0.f);
                    int col = wc * 96 + nt * 16 + l15;
                    int gg = col >> 3;
                    zin[er * 192 + ((gg ^ (er & 7)) << 3) + (col & 7)] = f2bf(v);
                }
            }
        __syncthreads();

        // ---- GEMM2: wave-owns-rows ----
        f32x4 a2[4];
        a2[0] = zz; a2[1] = zz; a2[2] = zz; a2[3] = zz;
        #pragma unroll
        for (int kc = 0; kc < 6; kc++) {
            int gg = kc * 4 + l4;
            int row = wid * 16 + l15;
            bf16x8 af = *(const bf16x8*)&zin[row * 192 + ((gg ^ (row & 7)) << 3)];
            #pragma unroll
            for (int nt = 0; nt < 4; nt++) {
                bf16x8 bg = *(const bf16x8*)&w2f[(size_t)((nt * 6 + kc) << 9) + (lane << 3)];
                a2[nt] = __builtin_amdgcn_mfma_f32_16x16x32_bf16(af, bg, a2[nt], 0, 0, 0);
            }
        }
        // ---- epilogue: + b2 + residual(LDS) ----
        int eb2 = wid * 16;
        #pragma unroll
        for (int r = 0; r < 4; r++) {
            int er = eb2 + l4 * 4 + r;
            size_t ge = (size_t)base + er;
            #pragma unroll
            for (int nt = 0; nt < 4; nt++) {
                int col = nt * 16 + l15;
                float v = a2[nt][r] + b2v[nt] + eres[er][col];
                eout[ge * 64 + col] = v;
            }
        }
        __syncthreads();   // all waves done with zin/eres before next tile's write
    }
#undef LOAD_TILE
}

extern "C" void kernel_launch(void* const* d_in, const int* in_sizes, int n_in,
                              void* d_out, int out_size, void* d_ws, size_t ws_size,
                              hipStream_t stream) {
    (void)in_sizes; (void)n_in; (void)out_size; (void)ws_size;
    const float* node_in = (const float*)d_in[0];
    const float* edge_in = (const float*)d_in[1];
    const int*   ei      = (const int*)d_in[2];
    const float* gat_lin_w = (const float*)d_in[3];
    const float* gat_lin_edge_w = (const float*)d_in[4];
    const float* att_src = (const float*)d_in[5];
    const float* att_dst = (const float*)d_in[6];
    const float* att_edge = (const float*)d_in[7];
    const float* gat_bias = (const float*)d_in[8];
    const float* ln_w = (const float*)d_in[9];
    const float* ln_b = (const float*)d_in[10];
    const float* eu_w1 = (const float*)d_in[11];
    const float* eu_b1 = (const float*)d_in[12];
    const float* eu_ln_w = (const float*)d_in[13];
    const float* eu_ln_b = (const float*)d_in[14];
    const float* eu_w2 = (const float*)d_in[15];
    const float* eu_b2 = (const float*)d_in[16];

    float* out_node = (float*)d_out;
    float* out_edge = out_node + (size_t)NN * DD;

    float* ws = (float*)d_ws;
    unsigned short* xh = (unsigned short*)ws; ws += (size_t)(NN * DD) / 2;  // bf16 xh
    unsigned short* xbf = (unsigned short*)ws; ws += (size_t)(NN * DD) / 2;
    float* a_src = ws; ws += (size_t)NN * HH;
    float* a_dst = ws; ws += (size_t)NN * HH;
    float* node_a = ws; ws += (size_t)NN * DD;
    float* node_b = ws; ws += (size_t)NN * DD;
    unsigned short* w1f_all = (unsigned short*)ws; ws += (LL * D3 * D3) / 2;
    unsigned short* w2f_all = (unsigned short*)ws; ws += (LL * DD * D3) / 2;
    float* V_all = ws; ws += LL * DD * HH;
    int* deg    = (int*)ws; ws += NN;
    int* cursor = (int*)ws; ws += NN;
    int* row    = (int*)ws; ws += NN + 4;
    int* pos    = (int*)ws; ws += NE;
    int* srcs   = (int*)ws; ws += NT;
    float* aedge_s = ws; ws += (size_t)NT * HH;   // a_edge (then ex) in dst-sorted order

    // ---- CSR build + weight prep (once; topology fixed across layers) ----
    hipMemsetAsync(deg, 0, NN * sizeof(int), stream);
    hipMemsetAsync(aedge_s, 0, (size_t)NT * HH * sizeof(float), stream);
    k_hist<<<2048, 256, 0, stream>>>(ei, deg);
    k_scan<<<1, 1024, 0, stream>>>(deg, row, cursor);
    k_scatter<<<2048, 256, 0, stream>>>(ei, cursor, pos, srcs);
    k_self<<<(NN + 255) / 256, 256, 0, stream>>>(row, srcs);
    k_prepall<<<LL * 194, 256, 0, stream>>>(eu_w1, eu_w2, gat_lin_edge_w, att_edge,
                                            w1f_all, w2f_all, V_all);

    for (int l = 0; l < LL; l++) {
        const float* ncur = (l == 0) ? node_in : ((l == 1) ? node_a : ((l == 2) ? node_b : node_a));
        float* nnext = (l == 0) ? node_a : ((l == 1) ? node_b : ((l == 2) ? node_a : out_node));
        const float* ecur = (l == 0) ? edge_in : out_edge;

        k_aedge<<<4096, 256, 0, stream>>>(ecur, pos, V_all + l * DD * HH, aedge_s);
        k_nodelin<<<12500, 256, 0, stream>>>(ncur, gat_lin_w, att_src, att_dst, xh, a_src, a_dst, l);
        k_attnfused<<<12500, 256, 0, stream>>>(row, srcs, aedge_s, a_src, a_dst, xh,
                                               gat_bias, ln_w, ln_b, ncur, nnext, xbf,
                                               l, (l < LL - 1) ? 1 : 0);
        k_edgemlp<<<EGRID, 256, 0, stream>>>(xbf, ecur, out_edge, ei,
                                             w1f_all + (size_t)l * D3 * D3,
                                             w2f_all + (size_t)l * DD * D3,
                                             eu_b1, eu_ln_w, eu_ln_b, eu_b2, l);
    }
}

// Round 22
// 2075.224 us; speedup vs baseline: 2.7404x; 2.7404x over previous
//
#include <hip/hip_runtime.h>
#include <hip/hip_bf16.h>

#define NN 50000
#define NE 1000000
#define DD 64
#define HH 4
#define LL 4
#define D3 192
#define NT (NE + NN)   // total sorted entries (edges + self loops)

typedef float f32x4 __attribute__((ext_vector_type(4)));
typedef short bf16x8 __attribute__((ext_vector_type(8)));

__device__ __forceinline__ unsigned short f2bf(float f){
    union { __hip_bfloat16 b; unsigned short u; } cv;
    cv.b = __float2bfloat16(f);
    return cv.u;
}
__device__ __forceinline__ float bf2f(unsigned short u){
    return __uint_as_float(((unsigned)u) << 16);
}
__device__ __forceinline__ unsigned pk2(float a, float b){
    union { __hip_bfloat162 v; unsigned u; } cv;
    cv.v = __float22bfloat162_rn(float2{a, b});
    return cv.u;
}
__device__ __forceinline__ float lrelu(float x){ return x > 0.f ? x : 0.2f * x; }

// ================= CSR build (once per call; topology fixed across layers) =================
__global__ __launch_bounds__(256) void k_hist(const int* __restrict__ ei, int* __restrict__ deg){
    for (int e = blockIdx.x * 256 + threadIdx.x; e < NE; e += gridDim.x * 256)
        atomicAdd(&deg[ei[NE + e]], 1);
}

__global__ __launch_bounds__(1024) void k_scan(const int* __restrict__ deg,
                                               int* __restrict__ row,
                                               int* __restrict__ cursor){
    __shared__ int sm[1024];
    __shared__ int carry_s;
    int t = threadIdx.x;
    if (t == 0) carry_s = 0;
    __syncthreads();
    for (int base = 0; base < NN; base += 1024) {
        int i = base + t;
        int v = (i < NN) ? deg[i] + 1 : 0;
        sm[t] = v;
        __syncthreads();
        for (int off = 1; off < 1024; off <<= 1) {
            int x = (t >= off) ? sm[t - off] : 0;
            __syncthreads();
            sm[t] += x;
            __syncthreads();
        }
        int incl = sm[t];
        int carry = carry_s;
        if (i < NN) {
            int excl = carry + incl - v;
            row[i] = excl;
            cursor[i] = excl;
        }
        __syncthreads();
        if (t == 1023) carry_s = carry + incl;
        __syncthreads();
    }
    if (t == 0) row[NN] = carry_s;
}

__global__ __launch_bounds__(256) void k_scatter(const int* __restrict__ ei,
                                                 int* __restrict__ cursor,
                                                 int* __restrict__ pos,
                                                 int* __restrict__ srcs){
    for (int e = blockIdx.x * 256 + threadIdx.x; e < NE; e += gridDim.x * 256) {
        int d = ei[NE + e];
        int j = atomicAdd(&cursor[d], 1);
        pos[e] = j;
        srcs[j] = ei[e];
    }
}

// self-loop entries at the end of each node's segment
__global__ __launch_bounds__(256) void k_self(const int* __restrict__ row,
                                              int* __restrict__ srcs){
    int n = blockIdx.x * 256 + threadIdx.x;
    if (n < NN) srcs[row[n + 1] - 1] = n;
}

// ================= upfront weight prep, ALL layers (fragment-major W) =================
__global__ __launch_bounds__(256) void k_prepall(const float* __restrict__ w1,
                                                 const float* __restrict__ w2,
                                                 const float* __restrict__ we,
                                                 const float* __restrict__ atte,
                                                 unsigned short* __restrict__ w1f_all,
                                                 unsigned short* __restrict__ w2f_all,
                                                 float* __restrict__ V_all){
    int l = blockIdx.x / 194;
    int i = (blockIdx.x % 194) * 256 + threadIdx.x;
    unsigned short* w1f = w1f_all + (size_t)l * D3 * D3;
    unsigned short* w2f = w2f_all + (size_t)l * DD * D3;
    float* V = V_all + l * DD * HH;
    if (i < 36864) {
        int c = i / 3072, r = i % 3072;
        int kc = r / 512, r2 = r % 512;
        int lane = r2 >> 3, m = r2 & 7;
        int k = kc * 32 + (lane >> 4) * 8 + m;
        int n = c * 16 + (lane & 15);
        w1f[i] = f2bf(w1[(size_t)l * D3 * D3 + k * D3 + n]);
    } else if (i < 49152) {
        int j = i - 36864;
        int c = j / 3072, r = j % 3072;
        int kc = r / 512, r2 = r % 512;
        int lane = r2 >> 3, m = r2 & 7;
        int k = kc * 32 + (lane >> 4) * 8 + m;
        int n = c * 16 + (lane & 15);
        w2f[j] = f2bf(w2[(size_t)l * D3 * DD + k * DD + n]);
    } else if (i < 49152 + DD * HH) {
        int j = i - 49152;
        int k = j >> 2, h = j & 3;
        float s = 0.f;
        #pragma unroll
        for (int c = 0; c < 16; c++)
            s += we[(size_t)l * DD * DD + k * DD + h * 16 + c] * atte[l * DD + h * 16 + c];
        V[j] = s;
    }
}

// ================= per-layer a_edge = ecur @ V(l), scattered to SORTED position =================
__global__ __launch_bounds__(256) void k_aedge(const float* __restrict__ ef,
                                               const int* __restrict__ pos,
                                               const float* __restrict__ Vg,
                                               float* __restrict__ aedge_s){
    __shared__ float Vl[256];
    Vl[threadIdx.x] = Vg[threadIdx.x];
    __syncthreads();
    int gk = threadIdx.x & 7;
    int em = threadIdx.x >> 3;
    int c0 = gk * 8;
    for (int eb = blockIdx.x * 32; eb < NE; eb += gridDim.x * 32) {
        int e = eb + em;
        const float4* ep = (const float4*)(ef + (size_t)e * 64 + c0);
        float4 v0 = ep[0];
        float4 v1 = ep[1];
        float p0, p1, p2, p3;
        {
            const float* Vp = &Vl[c0 * 4];
            p0 = v0.x*Vp[0] + v0.y*Vp[4] + v0.z*Vp[8]  + v0.w*Vp[12]
               + v1.x*Vp[16] + v1.y*Vp[20] + v1.z*Vp[24] + v1.w*Vp[28];
            p1 = v0.x*Vp[1] + v0.y*Vp[5] + v0.z*Vp[9]  + v0.w*Vp[13]
               + v1.x*Vp[17] + v1.y*Vp[21] + v1.z*Vp[25] + v1.w*Vp[29];
            p2 = v0.x*Vp[2] + v0.y*Vp[6] + v0.z*Vp[10] + v0.w*Vp[14]
               + v1.x*Vp[18] + v1.y*Vp[22] + v1.z*Vp[26] + v1.w*Vp[30];
            p3 = v0.x*Vp[3] + v0.y*Vp[7] + v0.z*Vp[11] + v0.w*Vp[15]
               + v1.x*Vp[19] + v1.y*Vp[23] + v1.z*Vp[27] + v1.w*Vp[31];
        }
        #pragma unroll
        for (int m = 1; m < 8; m <<= 1) {
            p0 += __shfl_xor(p0, m);
            p1 += __shfl_xor(p1, m);
            p2 += __shfl_xor(p2, m);
            p3 += __shfl_xor(p3, m);
        }
        if (gk == 0) {
            int j = pos[e];
            float4 ae = {p0, p1, p2, p3};
            *(float4*)(aedge_s + (size_t)j * 4) = ae;
        }
    }
}

// ================= node linear + attention coefficients (xh stored bf16) =================
__global__ __launch_bounds__(256) void k_nodelin(const float* __restrict__ x,
                                                 const float* __restrict__ Wg,
                                                 const float* __restrict__ attsrc,
                                                 const float* __restrict__ attdst,
                                                 unsigned short* __restrict__ xh,
                                                 float* __restrict__ a_src,
                                                 float* __restrict__ a_dst, int l){
    __shared__ float Wl[64 * 64];
    __shared__ float xr[4 * 64];
    int t = threadIdx.x;
    const float* W = Wg + (size_t)l * 4096;
    for (int i = t; i < 4096; i += 256) Wl[i] = W[i];
    int row = blockIdx.x * 4 + (t >> 6);
    int col = t & 63;
    if (row < NN) xr[t] = x[(size_t)row * 64 + col];
    __syncthreads();
    float acc = 0.f;
    const float* xp = &xr[(t >> 6) * 64];
    #pragma unroll
    for (int k = 0; k < 64; k++) acc += xp[k] * Wl[k * 64 + col];
    float ps = acc * attsrc[l * 64 + col];
    float pd = acc * attdst[l * 64 + col];
    #pragma unroll
    for (int m = 1; m < 16; m <<= 1) { ps += __shfl_xor(ps, m); pd += __shfl_xor(pd, m); }
    if (row < NN) {
        xh[(size_t)row * 64 + col] = f2bf(acc);
        if ((col & 15) == 0) {
            a_src[row * 4 + (col >> 4)] = ps;
            a_dst[row * 4 + (col >> 4)] = pd;
        }
    }
}

// ================= fused attention: softmax + aggregation + LN + residual, one wave per node ====
__global__ __launch_bounds__(256) void k_attnfused(const int* __restrict__ row,
                                                   const int* __restrict__ srcs,
                                                   float* __restrict__ aedge_s,
                                                   const float* __restrict__ a_src,
                                                   const float* __restrict__ a_dst,
                                                   const unsigned short* __restrict__ xh,
                                                   const float* __restrict__ bias,
                                                   const float* __restrict__ lnw,
                                                   const float* __restrict__ lnb,
                                                   const float* __restrict__ xcur,
                                                   float* __restrict__ xnext,
                                                   unsigned short* __restrict__ xbf,
                                                   int l, int dorelu){
    int n = blockIdx.x * 4 + (threadIdx.x >> 6);
    if (n >= NN) return;
    int lane = threadIdx.x & 63;
    int a = row[n], b = row[n + 1];
    int len = b - a;

    const float4 ad = *(const float4*)(a_dst + (size_t)n * 4);
    float4 mx = {-1e30f, -1e30f, -1e30f, -1e30f};
    float4 sum = {0.f, 0.f, 0.f, 0.f};

    if (len <= 64) {
        int j = a + lane;
        bool act = lane < len;
        float4 val = {-1e30f, -1e30f, -1e30f, -1e30f};
        if (act) {
            int s = srcs[j];
            const float4 as = *(const float4*)(a_src + (size_t)s * 4);
            const float4 ae = *(const float4*)(aedge_s + (size_t)j * 4);
            val.x = lrelu(as.x + ad.x + ae.x);
            val.y = lrelu(as.y + ad.y + ae.y);
            val.z = lrelu(as.z + ad.z + ae.z);
            val.w = lrelu(as.w + ad.w + ae.w);
        }
        mx = val;
        #pragma unroll
        for (int m = 1; m < 64; m <<= 1) {
            mx.x = fmaxf(mx.x, __shfl_xor(mx.x, m));
            mx.y = fmaxf(mx.y, __shfl_xor(mx.y, m));
            mx.z = fmaxf(mx.z, __shfl_xor(mx.z, m));
            mx.w = fmaxf(mx.w, __shfl_xor(mx.w, m));
        }
        float4 ex = {0.f, 0.f, 0.f, 0.f};
        if (act) {
            ex.x = expf(val.x - mx.x);
            ex.y = expf(val.y - mx.y);
            ex.z = expf(val.z - mx.z);
            ex.w = expf(val.w - mx.w);
            *(float4*)(aedge_s + (size_t)j * 4) = ex;
        }
        sum = ex;
        #pragma unroll
        for (int m = 1; m < 64; m <<= 1) {
            sum.x += __shfl_xor(sum.x, m);
            sum.y += __shfl_xor(sum.y, m);
            sum.z += __shfl_xor(sum.z, m);
            sum.w += __shfl_xor(sum.w, m);
        }
    } else {
        for (int j0 = a; j0 < b; j0 += 64) {
            int j = j0 + lane;
            if (j < b) {
                int s = srcs[j];
                const float4 as = *(const float4*)(a_src + (size_t)s * 4);
                const float4 ae = *(const float4*)(aedge_s + (size_t)j * 4);
                mx.x = fmaxf(mx.x, lrelu(as.x + ad.x + ae.x));
                mx.y = fmaxf(mx.y, lrelu(as.y + ad.y + ae.y));
                mx.z = fmaxf(mx.z, lrelu(as.z + ad.z + ae.z));
                mx.w = fmaxf(mx.w, lrelu(as.w + ad.w + ae.w));
            }
        }
        #pragma unroll
        for (int m = 1; m < 64; m <<= 1) {
            mx.x = fmaxf(mx.x, __shfl_xor(mx.x, m));
            mx.y = fmaxf(mx.y, __shfl_xor(mx.y, m));
            mx.z = fmaxf(mx.z, __shfl_xor(mx.z, m));
            mx.w = fmaxf(mx.w, __shfl_xor(mx.w, m));
        }
        for (int j0 = a; j0 < b; j0 += 64) {
            int j = j0 + lane;
            if (j < b) {
                int s = srcs[j];
                const float4 as = *(const float4*)(a_src + (size_t)s * 4);
                const float4 ae = *(const float4*)(aedge_s + (size_t)j * 4);
                float4 ex;
                ex.x = expf(lrelu(as.x + ad.x + ae.x) - mx.x);
                ex.y = expf(lrelu(as.y + ad.y + ae.y) - mx.y);
                ex.z = expf(lrelu(as.z + ad.z + ae.z) - mx.z);
                ex.w = expf(lrelu(as.w + ad.w + ae.w) - mx.w);
                *(float4*)(aedge_s + (size_t)j * 4) = ex;
                sum.x += ex.x; sum.y += ex.y; sum.z += ex.z; sum.w += ex.w;
            }
        }
        #pragma unroll
        for (int m = 1; m < 64; m <<= 1) {
            sum.x += __shfl_xor(sum.x, m);
            sum.y += __shfl_xor(sum.y, m);
            sum.z += __shfl_xor(sum.z, m);
            sum.w += __shfl_xor(sum.w, m);
        }
    }

    int h = lane >> 4;
    float sumh = (h == 0) ? sum.x : (h == 1) ? sum.y : (h == 2) ? sum.z : sum.w;
    float invh = 1.f / (sumh + 1e-16f);

    float accv = 0.f;
    #pragma unroll 8
    for (int j = a; j < b; ++j) {
        int s = srcs[j];
        float coef = aedge_s[(size_t)j * 4 + h] * invh;
        accv = fmaf(bf2f(xh[(size_t)s * 64 + lane]), coef, accv);
    }

    if (lane < 4) aedge_s[(size_t)(b - 1) * 4 + lane] = 0.f;

    float v = accv + bias[l * 64 + lane];
    float s = v, q = v * v;
    #pragma unroll
    for (int m = 1; m < 64; m <<= 1) { s += __shfl_xor(s, m); q += __shfl_xor(q, m); }
    float mu = s * (1.f / 64.f);
    float var = q * (1.f / 64.f) - mu * mu;
    float y = (v - mu) * rsqrtf(var + 1e-5f) * lnw[l * 64 + lane] + lnb[l * 64 + lane];
    if (dorelu) y = fmaxf(y, 0.f);
    float out = y + xcur[(size_t)n * 64 + lane];
    xnext[(size_t)n * 64 + lane] = out;
    xbf[(size_t)n * 64 + lane] = f2bf(out);
}

// ---------------- edge MLP (round-17/20 proven kernel, verbatim) ----------------
#define ET 64
__global__ __launch_bounds__(256, 4) void k_edgemlp(const unsigned short* __restrict__ xbf,
                                                    const float* __restrict__ ein,
                                                    float* __restrict__ eout,
                                                    const int* __restrict__ ei,
                                                    const unsigned short* __restrict__ w1f,
                                                    const unsigned short* __restrict__ w2f,
                                                    const float* __restrict__ b1g,
                                                    const float* __restrict__ lnwg,
                                                    const float* __restrict__ lnbg,
                                                    const float* __restrict__ b2g, int l){
    __shared__ __align__(16) unsigned short zin[ET * 192];  // 24.6KB
    __shared__ float red[ET][2][2];                         // 1KB
    __shared__ float eres[ET][68];                          // 17.4KB residual park

    int t = threadIdx.x;
    int base = blockIdx.x * ET;

    int wid = t >> 6, lane = t & 63;

    // ---- stage z = [xbf[src] | xbf[dst] | cvt(ein)]; ein fp32 parked in eres ----
    {
        int ge = base + lane;
        int sidx = ei[ge], didx = ei[NE + ge];
        #pragma unroll
        for (int i = 0; i < 6; i++) {
            int g = i * 4 + wid;          // wave-uniform
            uint4 wv;
            if (g < 16) {
                const unsigned short* srcb = (g < 8)
                    ? (xbf + (size_t)sidx * 64 + g * 8)
                    : (xbf + (size_t)didx * 64 + (g - 8) * 8);
                wv = *(const uint4*)srcb;
            } else {
                const float* src = ein + (size_t)ge * 64 + (g - 16) * 8;
                float4 v0 = *(const float4*)src;
                float4 v1 = *(const float4*)(src + 4);
                int c0 = (g - 16) * 8;
                eres[lane][c0 + 0] = v0.x; eres[lane][c0 + 1] = v0.y;
                eres[lane][c0 + 2] = v0.z; eres[lane][c0 + 3] = v0.w;
                eres[lane][c0 + 4] = v1.x; eres[lane][c0 + 5] = v1.y;
                eres[lane][c0 + 6] = v1.z; eres[lane][c0 + 7] = v1.w;
                wv.x = pk2(v0.x, v0.y); wv.y = pk2(v0.z, v0.w);
                wv.z = pk2(v1.x, v1.y); wv.w = pk2(v1.z, v1.w);
            }
            *(uint4*)&zin[lane * 192 + ((g ^ (lane & 7)) << 3)] = wv;
        }
    }
    __syncthreads();

    int wr = wid >> 1, wc = wid & 1;
    int l15 = lane & 15, l4 = lane >> 4;
    int eb = wr * 32;

    f32x4 zz = {0.f, 0.f, 0.f, 0.f};
    f32x4 acc[2][6];
    #pragma unroll
    for (int mt = 0; mt < 2; mt++)
        #pragma unroll
        for (int nt = 0; nt < 6; nt++) acc[mt][nt] = zz;

    #pragma unroll
    for (int kc = 0; kc < 6; kc++) {
        int ko = kc * 32 + l4 * 8;
        int gg = ko >> 3;
        bf16x8 af[2], bfv[6];
        #pragma unroll
        for (int mt = 0; mt < 2; mt++) {
            int row = eb + mt * 16 + l15;
            af[mt] = *(const bf16x8*)&zin[row * 192 + ((gg ^ (row & 7)) << 3)];
        }
        #pragma unroll
        for (int nt = 0; nt < 6; nt++)
            bfv[nt] = *(const bf16x8*)&w1f[(size_t)(((wc * 6 + nt) * 6 + kc) << 9) + (lane << 3)];
        #pragma unroll
        for (int mt = 0; mt < 2; mt++)
            #pragma unroll
            for (int nt = 0; nt < 6; nt++)
                acc[mt][nt] = __builtin_amdgcn_mfma_f32_16x16x32_bf16(af[mt], bfv[nt], acc[mt][nt], 0, 0, 0);
    }

    float b1v[6], lnwv[6], lnbv[6];
    #pragma unroll
    for (int nt = 0; nt < 6; nt++) {
        int col = wc * 96 + nt * 16 + l15;
        b1v[nt] = b1g[l * D3 + col];
        lnwv[nt] = lnwg[l * D3 + col];
        lnbv[nt] = lnbg[l * D3 + col];
    }
    float ps[2][4], pq[2][4];
    #pragma unroll
    for (int mt = 0; mt < 2; mt++)
        #pragma unroll
        for (int r = 0; r < 4; r++) {
            float s = 0.f, q = 0.f;
            #pragma unroll
            for (int nt = 0; nt < 6; nt++) {
                float v = acc[mt][nt][r] + b1v[nt];
                acc[mt][nt][r] = v;
                s += v; q += v * v;
            }
            #pragma unroll
            for (int m = 1; m < 16; m <<= 1) { s += __shfl_xor(s, m); q += __shfl_xor(q, m); }
            ps[mt][r] = s; pq[mt][r] = q;
        }
    if (l15 == 0) {
        #pragma unroll
        for (int mt = 0; mt < 2; mt++)
            #pragma unroll
            for (int r = 0; r < 4; r++) {
                int er = eb + mt * 16 + l4 * 4 + r;
                red[er][wc][0] = ps[mt][r];
                red[er][wc][1] = pq[mt][r];
            }
    }
    __syncthreads();

    #pragma unroll
    for (int mt = 0; mt < 2; mt++)
        #pragma unroll
        for (int r = 0; r < 4; r++) {
            int er = eb + mt * 16 + l4 * 4 + r;
            float s = red[er][0][0] + red[er][1][0];
            float q = red[er][0][1] + red[er][1][1];
            float mu = s * (1.f / 192.f);
            float rs = rsqrtf(q * (1.f / 192.f) - mu * mu + 1e-5f);
            #pragma unroll
            for (int nt = 0; nt < 6; nt++) {
                float v = (acc[mt][nt][r] - mu) * rs * lnwv[nt] + lnbv[nt];
                v = fmaxf(v, 0.f);
                int col = wc * 96 + nt * 16 + l15;
                int gg = col >> 3;
                zin[er * 192 + ((gg ^ (er & 7)) << 3) + (col & 7)] = f2bf(v);
            }
        }
    __syncthreads();

    // ---- GEMM2: wave-owns-rows (16 edges x 64 cols per wave) ----
    f32x4 a2[4];
    a2[0] = zz; a2[1] = zz; a2[2] = zz; a2[3] = zz;
    #pragma unroll
    for (int kc = 0; kc < 6; kc++) {
        int ko = kc * 32 + l4 * 8;
        int gg = ko >> 3;
        int row = wid * 16 + l15;
        bf16x8 af = *(const bf16x8*)&zin[row * 192 + ((gg ^ (row & 7)) << 3)];
        #pragma unroll
        for (int nt = 0; nt < 4; nt++) {
            bf16x8 bg = *(const bf16x8*)&w2f[(size_t)((nt * 6 + kc) << 9) + (lane << 3)];
            a2[nt] = __builtin_amdgcn_mfma_f32_16x16x32_bf16(af, bg, a2[nt], 0, 0, 0);
        }
    }
    // ---- epilogue: + b2 + residual(LDS); r-outer/nt-inner so one wave closes each 256B line ----
    int eb2 = wid * 16;
    #pragma unroll
    for (int r = 0; r < 4; r++) {
        int er = eb2 + l4 * 4 + r;
        size_t ge = (size_t)base + er;
        #pragma unroll
        for (int nt = 0; nt < 4; nt++) {
            int col = nt * 16 + l15;
            float v = a2[nt][r] + b2g[l * 64 + col] + eres[er][col];
            eout[ge * 64 + col] = v;
        }
    }
}

extern "C" void kernel_launch(void* const* d_in, const int* in_sizes, int n_in,
                              void* d_out, int out_size, void* d_ws, size_t ws_size,
                              hipStream_t stream) {
    (void)in_sizes; (void)n_in; (void)out_size; (void)ws_size;
    const float* node_in = (const float*)d_in[0];
    const float* edge_in = (const float*)d_in[1];
    const int*   ei      = (const int*)d_in[2];
    const float* gat_lin_w = (const float*)d_in[3];
    const float* gat_lin_edge_w = (const float*)d_in[4];
    const float* att_src = (const float*)d_in[5];
    const float* att_dst = (const float*)d_in[6];
    const float* att_edge = (const float*)d_in[7];
    const float* gat_bias = (const float*)d_in[8];
    const float* ln_w = (const float*)d_in[9];
    const float* ln_b = (const float*)d_in[10];
    const float* eu_w1 = (const float*)d_in[11];
    const float* eu_b1 = (const float*)d_in[12];
    const float* eu_ln_w = (const float*)d_in[13];
    const float* eu_ln_b = (const float*)d_in[14];
    const float* eu_w2 = (const float*)d_in[15];
    const float* eu_b2 = (const float*)d_in[16];

    float* out_node = (float*)d_out;
    float* out_edge = out_node + (size_t)NN * DD;

    float* ws = (float*)d_ws;
    unsigned short* xh = (unsigned short*)ws; ws += (size_t)(NN * DD) / 2;  // bf16 xh
    unsigned short* xbf = (unsigned short*)ws; ws += (size_t)(NN * DD) / 2;
    float* a_src = ws; ws += (size_t)NN * HH;
    float* a_dst = ws; ws += (size_t)NN * HH;
    float* node_a = ws; ws += (size_t)NN * DD;
    float* node_b = ws; ws += (size_t)NN * DD;
    unsigned short* w1f_all = (unsigned short*)ws; ws += (LL * D3 * D3) / 2;
    unsigned short* w2f_all = (unsigned short*)ws; ws += (LL * DD * D3) / 2;
    float* V_all = ws; ws += LL * DD * HH;
    int* deg    = (int*)ws; ws += NN;
    int* cursor = (int*)ws; ws += NN;
    int* row    = (int*)ws; ws += NN + 4;
    int* pos    = (int*)ws; ws += NE;
    int* srcs   = (int*)ws; ws += NT;
    float* aedge_s = ws; ws += (size_t)NT * HH;   // a_edge (then ex) in dst-sorted order

    // ---- CSR build + weight prep (once; topology fixed across layers) ----
    hipMemsetAsync(deg, 0, NN * sizeof(int), stream);
    hipMemsetAsync(aedge_s, 0, (size_t)NT * HH * sizeof(float), stream);
    k_hist<<<2048, 256, 0, stream>>>(ei, deg);
    k_scan<<<1, 1024, 0, stream>>>(deg, row, cursor);
    k_scatter<<<2048, 256, 0, stream>>>(ei, cursor, pos, srcs);
    k_self<<<(NN + 255) / 256, 256, 0, stream>>>(row, srcs);
    k_prepall<<<LL * 194, 256, 0, stream>>>(eu_w1, eu_w2, gat_lin_edge_w, att_edge,
                                            w1f_all, w2f_all, V_all);

    for (int l = 0; l < LL; l++) {
        const float* ncur = (l == 0) ? node_in : ((l == 1) ? node_a : ((l == 2) ? node_b : node_a));
        float* nnext = (l == 0) ? node_a : ((l == 1) ? node_b : ((l == 2) ? node_a : out_node));
        const float* ecur = (l == 0) ? edge_in : out_edge;

        k_aedge<<<4096, 256, 0, stream>>>(ecur, pos, V_all + l * DD * HH, aedge_s);
        k_nodelin<<<12500, 256, 0, stream>>>(ncur, gat_lin_w, att_src, att_dst, xh, a_src, a_dst, l);
        k_attnfused<<<12500, 256, 0, stream>>>(row, srcs, aedge_s, a_src, a_dst, xh,
                                               gat_bias, ln_w, ln_b, ncur, nnext, xbf,
                                               l, (l < LL - 1) ? 1 : 0);
        k_edgemlp<<<NE / ET, 256, 0, stream>>>(xbf, ecur, out_edge, ei,
                                               w1f_all + (size_t)l * D3 * D3,
                                               w2f_all + (size_t)l * DD * D3,
                                               eu_b1, eu_ln_w, eu_ln_b, eu_b2, l);
    }
}